// Round 1
// baseline (433.985 us; speedup 1.0000x reference)
//
#include <hip/hip_runtime.h>

// Problem constants (fixed by setup_inputs)
#define BATCH    4
#define NQ       10000
#define EMB      256
#define NH       8
#define DH       32
#define NL       4
#define NP       8
#define S_TOTAL  19560
#define NROW     (BATCH * NQ)          // 40000
#define VROWS    (BATCH * S_TOTAL)     // 78240

typedef _Float16 half8 __attribute__((ext_vector_type(8)));
typedef _Float16 half4v __attribute__((ext_vector_type(4)));
typedef _Float16 half2v __attribute__((ext_vector_type(2)));
typedef float floatx4 __attribute__((ext_vector_type(4)));

// ---------------------------------------------------------------------------
// One-shot weight prep: transpose+swizzle all three weight matrices to f16.
// Logical row n (0..1279): [0,512) w_off -> wT768, [512,768) w_attn -> wT768,
// [768,1280) ... w_val (256 rows) -> wvaT. Swizzle: 16B chunk c of row n
// lands at chunk c ^ (n&7) (row-local n; offsets are multiples of 8 so &7 is
// preserved).
// ---------------------------------------------------------------------------
__global__ __launch_bounds__(256) void prep_weights(
    const float* __restrict__ w_off, const float* __restrict__ w_attn,
    const float* __restrict__ w_val, _Float16* __restrict__ wT768,
    _Float16* __restrict__ wvaT) {
  const int tid = blockIdx.x * 256 + threadIdx.x;   // over 1024*256
  const int n = tid >> 8, k = tid & 255;
  const int c = k >> 3, e = k & 7;
  const int swz = ((c ^ (n & 7)) << 3) + e;
  float v;
  _Float16* dst;
  if (n < 512)      { v = w_off[(size_t)k * 512 + n];          dst = wT768 + (size_t)n * 256; }
  else if (n < 768) { v = w_attn[(size_t)k * 256 + (n - 512)]; dst = wT768 + (size_t)n * 256; }
  else              { v = w_val[(size_t)k * 256 + (n - 768)];  dst = wvaT + (size_t)(n - 768) * 256; }
  dst[swz] = (_Float16)v;
}

// ---------------------------------------------------------------------------
// MFMA GEMM: A-register-resident + B-chunk-in-LDS, 3 blocks/CU.
//   C = A[M,256]_f32 @ WTs[NC,256]^T + bias(col-select)
// Block: 256 thr = 4 waves x 32 rows = 128 rows. Each wave:
//   1. loads its 32 A rows (f32, HBM, ONCE) -> f16 in-reg (a[2][8], 64 VGPR)
//   2. per 64-col chunk: block stages B (64x256 f16 = 32 KB, swizzled) into
//      LDS (8 half8/thread), then 8 k-steps x 8 MFMA, no global deps.
// Bias: col < SPLITC ? bias0[col] : bias1[col-SPLITC].
// SWZ=true scatters C into [B, H, S, 32] layout for the sampler.
// ---------------------------------------------------------------------------
template <int NC, int NYS, bool SWZ>
__global__ __launch_bounds__(256, 3) void gemm5(
    const float* __restrict__ A, const _Float16* __restrict__ WTs,
    const float* __restrict__ bias0, const float* __restrict__ bias1,
    int splitc, _Float16* __restrict__ C, int M) {
  __shared__ _Float16 bsm[64 * 256];   // 32 KB B chunk (swizzled rows)
  const int t = threadIdx.x;
  const int wave = t >> 6, lane = t & 63;
  const int l15 = lane & 15, quad = lane >> 4;
  const int m0 = blockIdx.x * 128 + wave * 32;
  const int nlo = blockIdx.y * (NC / NYS);
  const int nchunks = (NC / NYS) / 64;

  // ---- load + convert the wave's A slice (32 rows x 256) ----
  half8 a[2][8];
  #pragma unroll
  for (int i = 0; i < 2; ++i) {
    const float* Ar = A + (size_t)min(m0 + 16 * i + l15, M - 1) * 256 + quad * 8;
    #pragma unroll
    for (int ks = 0; ks < 8; ++ks) {
      const float4 f0 = *(const float4*)(Ar + ks * 32);
      const float4 f1 = *(const float4*)(Ar + ks * 32 + 4);
      a[i][ks][0] = (_Float16)f0.x; a[i][ks][1] = (_Float16)f0.y;
      a[i][ks][2] = (_Float16)f0.z; a[i][ks][3] = (_Float16)f0.w;
      a[i][ks][4] = (_Float16)f1.x; a[i][ks][5] = (_Float16)f1.y;
      a[i][ks][6] = (_Float16)f1.z; a[i][ks][7] = (_Float16)f1.w;
    }
  }

  const _Float16* src = WTs + (size_t)nlo * 256;

  for (int ch = 0; ch < nchunks; ++ch) {
    // ---- stage B chunk: 64x256 f16 = 2048 half8; 8 half8 per thread ----
    __syncthreads();
    #pragma unroll
    for (int i = 0; i < 8; ++i)
      *(half8*)&bsm[t * 8 + i * 2048] = *(const half8*)(src + t * 8 + i * 2048);
    __syncthreads();

    floatx4 acc[2][4] = {};
    #pragma unroll
    for (int ks = 0; ks < 8; ++ks) {
      half8 b[4];
      #pragma unroll
      for (int j = 0; j < 4; ++j)
        b[j] = *(const half8*)&bsm[(16 * j + l15) * 256 +
                                   ((((ks * 4 + quad) ^ (l15 & 7))) << 3)];
      #pragma unroll
      for (int j = 0; j < 4; ++j)
        #pragma unroll
        for (int i = 0; i < 2; ++i)
          acc[i][j] = __builtin_amdgcn_mfma_f32_16x16x32_f16(a[i][ks], b[j], acc[i][j], 0, 0, 0);
    }

    const int nc0 = nlo + ch * 64;
    float bc[4];
    #pragma unroll
    for (int j = 0; j < 4; ++j) {
      const int col = nc0 + 16 * j + l15;
      bc[j] = (col < splitc) ? bias0[col] : bias1[col - splitc];
    }

    #pragma unroll
    for (int i = 0; i < 2; ++i) {
      #pragma unroll
      for (int r = 0; r < 4; ++r) {
        const int row = m0 + 16 * i + quad * 4 + r;
        if (row < M) {
          if (SWZ) {
            const int b = row / S_TOTAL;
            const int s = row - b * S_TOTAL;
            #pragma unroll
            for (int j = 0; j < 4; ++j) {
              const int col = nc0 + 16 * j + l15;
              const size_t dst =
                  (((size_t)b * NH + (col >> 5)) * S_TOTAL + s) * 32 + (col & 31);
              C[dst] = (_Float16)(acc[i][j][r] + bc[j]);
            }
          } else {
            #pragma unroll
            for (int j = 0; j < 4; ++j)
              C[(size_t)row * NC + nc0 + 16 * j + l15] =
                  (_Float16)(acc[i][j][r] + bc[j]);
          }
        }
      }
    }
    src += 64 * 256;
  }
}

// ---------------------------------------------------------------------------
// Fused softmax + deformable bilinear sampling. vproj [B,H,S,32];
// XCD-pinned batches; rowpair 2-segment gathers.
//
// Round-9 restructure: 512 threads/query (full 64-lane wave per head).
//   Phase 1 (address/weight setup) is computed redundantly by t and t+256
//   (identical values, distinct waves -> no LDS conflicts).
//   Phase 2: per lane 8 gathers of half8 (16B) instead of 32 of half4 (8B).
//   Round-8 evidence: VGPR_Count=40 proved the compiler re-serialized the 32
//   in-flight 8B loads (needed 64 VGPRs of results). 8x16B results need only
//   32 VGPRs -> all gathers genuinely in flight; per-thread VALU ~halved.
//   wl/wr merged into one LDS array so side-select is address math.
// __launch_bounds__(512,6) -> <=85 VGPR -> 3 blocks = 24 waves/CU.
// ---------------------------------------------------------------------------
__global__ __launch_bounds__(512, 6) void msda_sample(
    const _Float16* __restrict__ vproj,     // [B,H,S,32] f16 (+guards)
    const _Float16* __restrict__ fused,     // [B*Q, 768] f16: off(512)|logit(256)
    const float* __restrict__ ref,          // [B*Q, 4, 2] f32
    float* __restrict__ out) {              // [B*Q, 256] f32
  const int lvl_h[NL] = {92, 46, 23, 12};
  const int lvl_w[NL] = {160, 80, 40, 20};
  const int lvl_s[NL] = {0, 14720, 18400, 19320};

  __shared__ int   addr_s[512];   // [(h*32+lp)*2 + rp]
  __shared__ float w2_s[1024];    // [side*512 + (h*32+lp)*2 + rp]

  const int t   = threadIdx.x;    // 0..511
  const int t2  = t & 255;        // phase-1 role (duplicated across halves)
  const int blk = blockIdx.x;
  const int b   = blk & 3;             // pins batch to XCD (blk%8 round-robin)
  const int q   = blk >> 2;
  const int row = b * NQ + q;

  const int h1 = t2 >> 5;
  const int lp = t2 & 31;
  const int l  = lp >> 3;
  const int p  = lp & 7;

  // ---- softmax over the 32 (l,p) logits of this head (xor shuffles) ----
  const float logit = (float)fused[(size_t)row * 768 + 512 + t2];
  float mxv = logit;
  #pragma unroll
  for (int m = 1; m < 32; m <<= 1) mxv = fmaxf(mxv, __shfl_xor(mxv, m));
  const float e = __expf(logit - mxv);
  float sum = e;
  #pragma unroll
  for (int m = 1; m < 32; m <<= 1) sum += __shfl_xor(sum, m);
  const float attnw = e / sum;

  // ---- location & bilinear setup ----
  const half2v o2 = *(const half2v*)(fused + (size_t)row * 768 + 2 * t2);
  const float ox = (float)o2[0], oy = (float)o2[1];
  const int z = p & 3;                       // NP=8 split (2,4): z = p % 4
  const float rx = ref[((size_t)row * 4 + z) * 2 + 0];
  const float ry = ref[((size_t)row * 4 + z) * 2 + 1];
  const int Wl = lvl_w[l], Hl = lvl_h[l], st = lvl_s[l];

  const float px = fmaf(rx, (float)Wl, ox) - 0.5f;
  const float py = fmaf(ry, (float)Hl, oy) - 0.5f;
  const float x0f = floorf(px), y0f = floorf(py);
  const float wx = px - x0f, wy = py - y0f;
  const int x0 = (int)x0f, y0 = (int)y0f;
  const int x1 = x0 + 1,   y1 = y0 + 1;

  // x: one 128B segment based at xb covers slots xb (left) and xb+1 (right)
  const float mx0 = (x0 >= 0 && x0 < Wl) ? 1.f : 0.f;
  const float mx1 = (x1 >= 0 && x1 < Wl) ? 1.f : 0.f;
  const float my0 = (y0 >= 0 && y0 < Hl) ? 1.f : 0.f;
  const float my1 = (y1 >= 0 && y1 < Hl) ? 1.f : 0.f;
  const int xb  = min(max(x0, -1), Wl - 1);          // guard pages cover x=-1/W
  const int cy0 = min(max(y0, 0), Hl - 1);
  const int cy1 = min(max(y1, 0), Hl - 1);

  const int bh   = b * NH + h1;
  const int lbase = bh * S_TOTAL + st;
  const float wlc = attnw * (1.f - wx) * mx0;
  const float wrc = attnw * wx * mx1;

  addr_s[2 * t2 + 0] = (lbase + cy0 * Wl + xb) * 32;
  addr_s[2 * t2 + 1] = (lbase + cy1 * Wl + xb) * 32;
  w2_s[2 * t2 + 0]       = wlc * (1.f - wy) * my0;   // left,  top row
  w2_s[2 * t2 + 1]       = wlc * wy * my1;           // left,  bottom row
  w2_s[512 + 2 * t2 + 0] = wrc * (1.f - wy) * my0;   // right, top row
  w2_s[512 + 2 * t2 + 1] = wrc * wy * my1;           // right, bottom row
  __syncthreads();

  // ---- phase 2: full wave per head. g = (pp, sd, c2) ----
  const int h  = t >> 6;          // head 0..7
  const int g  = t & 63;
  const int c2 = g & 3;           // channel oct: channels 8*c2..8*c2+7
  const int sd = (g >> 2) & 1;    // 0 = left corner, 1 = right corner
  const int pp = g >> 3;          // point phase 0..7; lane covers points pp+8*ii
  const int ldoff = sd * 32 + 8 * c2;
  const int wbase = sd << 9;

  // gather addresses + weights (LDS), then issue ALL 8 global loads
  int bidx[4];
  #pragma unroll
  for (int ii = 0; ii < 4; ++ii)
    bidx[ii] = ((h << 5) + (ii << 3) + pp) << 1;

  int at[4], ab[4];
  #pragma unroll
  for (int ii = 0; ii < 4; ++ii) {
    at[ii] = addr_s[bidx[ii]];
    ab[ii] = addr_s[bidx[ii] + 1];
  }

  half8 vt[4], vb[4];
  #pragma unroll
  for (int ii = 0; ii < 4; ++ii) {
    vt[ii] = *(const half8*)(vproj + at[ii] + ldoff);
    vb[ii] = *(const half8*)(vproj + ab[ii] + ldoff);
  }

  float wt[4], wb[4];
  #pragma unroll
  for (int ii = 0; ii < 4; ++ii) {
    wt[ii] = w2_s[wbase + bidx[ii]];
    wb[ii] = w2_s[wbase + bidx[ii] + 1];
  }

  float a[8] = {0.f, 0.f, 0.f, 0.f, 0.f, 0.f, 0.f, 0.f};
  #pragma unroll
  for (int ii = 0; ii < 4; ++ii) {
    #pragma unroll
    for (int ch = 0; ch < 8; ++ch) {
      a[ch] = fmaf(wt[ii], (float)vt[ii][ch], a[ch]);
      a[ch] = fmaf(wb[ii], (float)vb[ii][ch], a[ch]);
    }
  }

  // reduce over side (xor 4) and point phase (xor 8,16,32)
  #pragma unroll
  for (int m = 4; m <= 32; m <<= 1) {
    #pragma unroll
    for (int ch = 0; ch < 8; ++ch) a[ch] += __shfl_xor(a[ch], m);
  }

  if ((g & 60) == 0) {   // sd==0 && pp==0: 4 lanes own the 4 channel octs
    float* op = out + (size_t)row * 256 + (h << 5) + (c2 << 3);
    float4 o0; o0.x = a[0]; o0.y = a[1]; o0.z = a[2]; o0.w = a[3];
    float4 o1; o1.x = a[4]; o1.y = a[5]; o1.z = a[6]; o1.w = a[7];
    *(float4*)op = o0;
    *(float4*)(op + 4) = o1;
  }
}

extern "C" void kernel_launch(void* const* d_in, const int* in_sizes, int n_in,
                              void* d_out, int out_size, void* d_ws, size_t ws_size,
                              hipStream_t stream) {
  const float* query  = (const float*)d_in[0];  // [4,10000,256]
  const float* value  = (const float*)d_in[1];  // [4,19560,256]
  const float* refpts = (const float*)d_in[2];  // [4,10000,4,2]
  const float* w_off  = (const float*)d_in[3];  // [256,512]
  const float* b_off  = (const float*)d_in[4];  // [512]
  const float* w_attn = (const float*)d_in[5];  // [256,256]
  const float* b_attn = (const float*)d_in[6];  // [256]
  const float* w_val  = (const float*)d_in[7];  // [256,256]
  const float* b_val  = (const float*)d_in[8];  // [256]
  float* out = (float*)d_out;

  // workspace layout (16B-multiple segments; 256B guards around vh for the
  // x=-1 / x=W edge reads, whose weights are zero)
  char* p = (char*)d_ws;
  p += 256;                                                         // front guard
  _Float16* vh    = (_Float16*)p;  p += (size_t)VROWS * 256 * 2;    // 40.1 MB
  p += 256;                                                         // back guard
  _Float16* wT768 = (_Float16*)p;  p += (size_t)768 * 256 * 2;      // swizzled
  _Float16* wvaT  = (_Float16*)p;  p += (size_t)256 * 256 * 2;      // swizzled
  _Float16* fused_h = (_Float16*)p; p += (size_t)NROW * 768 * 2;    // 61.4 MB

  // prep: all weight transposes in one launch
  prep_weights<<<1024, 256, 0, stream>>>(w_off, w_attn, w_val, wT768, wvaT);

  // GEMMs: A register-resident, B chunks via LDS.
  // v = value@w_val -> [B,H,S,32] swizzled; fused = query@[w_off|w_attn]
  gemm5<256, 1, true><<<dim3((VROWS + 127) / 128, 1), 256, 0, stream>>>(
      value, wvaT, b_val, b_val, 1 << 30, vh, VROWS);
  gemm5<768, 2, false><<<dim3((NROW + 127) / 128, 2), 256, 0, stream>>>(
      query, wT768, b_off, b_attn, 512, fused_h, NROW);

  // softmax + sample + weighted sum
  msda_sample<<<dim3(NROW), 512, 0, stream>>>(vh, fused_h, refpts, out);
}

// Round 2
// 412.633 us; speedup vs baseline: 1.0517x; 1.0517x over previous
//
#include <hip/hip_runtime.h>

// Problem constants (fixed by setup_inputs)
#define BATCH    4
#define NQ       10000
#define EMB      256
#define NH       8
#define DH       32
#define NL       4
#define NP       8
#define S_TOTAL  19560
#define NROW     (BATCH * NQ)          // 40000
#define VROWS    (BATCH * S_TOTAL)     // 78240

typedef _Float16 half8 __attribute__((ext_vector_type(8)));
typedef _Float16 half4v __attribute__((ext_vector_type(4)));
typedef _Float16 half2v __attribute__((ext_vector_type(2)));
typedef float floatx4 __attribute__((ext_vector_type(4)));

// ---------------------------------------------------------------------------
// One-shot weight prep: transpose+swizzle all three weight matrices to f16.
// Logical row n (0..1279): [0,512) w_off -> wT768, [512,768) w_attn -> wT768,
// [768,1280) ... w_val (256 rows) -> wvaT. Swizzle: 16B chunk c of row n
// lands at chunk c ^ (n&7) (row-local n; offsets are multiples of 8 so &7 is
// preserved).
// ---------------------------------------------------------------------------
__global__ __launch_bounds__(256) void prep_weights(
    const float* __restrict__ w_off, const float* __restrict__ w_attn,
    const float* __restrict__ w_val, _Float16* __restrict__ wT768,
    _Float16* __restrict__ wvaT) {
  const int tid = blockIdx.x * 256 + threadIdx.x;   // over 1024*256
  const int n = tid >> 8, k = tid & 255;
  const int c = k >> 3, e = k & 7;
  const int swz = ((c ^ (n & 7)) << 3) + e;
  float v;
  _Float16* dst;
  if (n < 512)      { v = w_off[(size_t)k * 512 + n];          dst = wT768 + (size_t)n * 256; }
  else if (n < 768) { v = w_attn[(size_t)k * 256 + (n - 512)]; dst = wT768 + (size_t)n * 256; }
  else              { v = w_val[(size_t)k * 256 + (n - 768)];  dst = wvaT + (size_t)(n - 768) * 256; }
  dst[swz] = (_Float16)v;
}

// ---------------------------------------------------------------------------
// MFMA GEMM: A-register-resident + B-chunk-in-LDS, 3 blocks/CU.
//   C = A[M,256]_f32 @ WTs[NC,256]^T + bias(col-select)
// Block: 256 thr = 4 waves x 32 rows = 128 rows. Each wave:
//   1. loads its 32 A rows (f32, HBM, ONCE) -> f16 in-reg (a[2][8], 64 VGPR)
//   2. per 64-col chunk: block stages B (64x256 f16 = 32 KB, swizzled) into
//      LDS (8 half8/thread), then 8 k-steps x 8 MFMA, no global deps.
// Bias: col < SPLITC ? bias0[col] : bias1[col-SPLITC].
// SWZ=true scatters C into [B, H, S, 32] layout for the sampler.
// ---------------------------------------------------------------------------
template <int NC, int NYS, bool SWZ>
__global__ __launch_bounds__(256, 3) void gemm5(
    const float* __restrict__ A, const _Float16* __restrict__ WTs,
    const float* __restrict__ bias0, const float* __restrict__ bias1,
    int splitc, _Float16* __restrict__ C, int M) {
  __shared__ _Float16 bsm[64 * 256];   // 32 KB B chunk (swizzled rows)
  const int t = threadIdx.x;
  const int wave = t >> 6, lane = t & 63;
  const int l15 = lane & 15, quad = lane >> 4;
  const int m0 = blockIdx.x * 128 + wave * 32;
  const int nlo = blockIdx.y * (NC / NYS);
  const int nchunks = (NC / NYS) / 64;

  // ---- load + convert the wave's A slice (32 rows x 256) ----
  half8 a[2][8];
  #pragma unroll
  for (int i = 0; i < 2; ++i) {
    const float* Ar = A + (size_t)min(m0 + 16 * i + l15, M - 1) * 256 + quad * 8;
    #pragma unroll
    for (int ks = 0; ks < 8; ++ks) {
      const float4 f0 = *(const float4*)(Ar + ks * 32);
      const float4 f1 = *(const float4*)(Ar + ks * 32 + 4);
      a[i][ks][0] = (_Float16)f0.x; a[i][ks][1] = (_Float16)f0.y;
      a[i][ks][2] = (_Float16)f0.z; a[i][ks][3] = (_Float16)f0.w;
      a[i][ks][4] = (_Float16)f1.x; a[i][ks][5] = (_Float16)f1.y;
      a[i][ks][6] = (_Float16)f1.z; a[i][ks][7] = (_Float16)f1.w;
    }
  }

  const _Float16* src = WTs + (size_t)nlo * 256;

  for (int ch = 0; ch < nchunks; ++ch) {
    // ---- stage B chunk: 64x256 f16 = 2048 half8; 8 half8 per thread ----
    __syncthreads();
    #pragma unroll
    for (int i = 0; i < 8; ++i)
      *(half8*)&bsm[t * 8 + i * 2048] = *(const half8*)(src + t * 8 + i * 2048);
    __syncthreads();

    floatx4 acc[2][4] = {};
    #pragma unroll
    for (int ks = 0; ks < 8; ++ks) {
      half8 b[4];
      #pragma unroll
      for (int j = 0; j < 4; ++j)
        b[j] = *(const half8*)&bsm[(16 * j + l15) * 256 +
                                   ((((ks * 4 + quad) ^ (l15 & 7))) << 3)];
      #pragma unroll
      for (int j = 0; j < 4; ++j)
        #pragma unroll
        for (int i = 0; i < 2; ++i)
          acc[i][j] = __builtin_amdgcn_mfma_f32_16x16x32_f16(a[i][ks], b[j], acc[i][j], 0, 0, 0);
    }

    const int nc0 = nlo + ch * 64;
    float bc[4];
    #pragma unroll
    for (int j = 0; j < 4; ++j) {
      const int col = nc0 + 16 * j + l15;
      bc[j] = (col < splitc) ? bias0[col] : bias1[col - splitc];
    }

    #pragma unroll
    for (int i = 0; i < 2; ++i) {
      #pragma unroll
      for (int r = 0; r < 4; ++r) {
        const int row = m0 + 16 * i + quad * 4 + r;
        if (row < M) {
          if (SWZ) {
            const int b = row / S_TOTAL;
            const int s = row - b * S_TOTAL;
            #pragma unroll
            for (int j = 0; j < 4; ++j) {
              const int col = nc0 + 16 * j + l15;
              const size_t dst =
                  (((size_t)b * NH + (col >> 5)) * S_TOTAL + s) * 32 + (col & 31);
              C[dst] = (_Float16)(acc[i][j][r] + bc[j]);
            }
          } else {
            #pragma unroll
            for (int j = 0; j < 4; ++j)
              C[(size_t)row * NC + nc0 + 16 * j + l15] =
                  (_Float16)(acc[i][j][r] + bc[j]);
          }
        }
      }
    }
    src += 64 * 256;
  }
}

// ---------------------------------------------------------------------------
// Fused softmax + deformable bilinear sampling. vproj [B,H,S,32];
// XCD-pinned batches; rowpair 2-segment gathers.
//
// Round-10: revert to the 256-thread round-8 geometry (round-9's 512-thread
// variant added ~37us of VALU work: redundant phase 1, 4-stage x 8-ch
// reduce). Two changes vs round-8:
//   * merged weight array w2_s (side-select is +512 address offset, no
//     cndmask chains) -- kept from round-9, pure win.
//   * __builtin_amdgcn_sched_barrier(0) between the 32 global-load issues
//     and the FMA loop. Evidence: VGPR_Count=40 (r8) and 32 (r9) prove the
//     scheduler re-serializes source-level load batches; the fence is the
//     only way to force all 32 results live (MLP). Expect VGPR ~110.
// Weight ds_reads stay AFTER the fence so their latency hides under vmcnt.
// __launch_bounds__(256,4) licenses 128 VGPR (4 waves/SIMD).
// ---------------------------------------------------------------------------
__global__ __launch_bounds__(256, 4) void msda_sample(
    const _Float16* __restrict__ vproj,     // [B,H,S,32] f16 (+guards)
    const _Float16* __restrict__ fused,     // [B*Q, 768] f16: off(512)|logit(256)
    const float* __restrict__ ref,          // [B*Q, 4, 2] f32
    float* __restrict__ out) {              // [B*Q, 256] f32
  const int lvl_h[NL] = {92, 46, 23, 12};
  const int lvl_w[NL] = {160, 80, 40, 20};
  const int lvl_s[NL] = {0, 14720, 18400, 19320};

  __shared__ int   addr_s[512];   // [(h*32+lp)*2 + rp]
  __shared__ float w2_s[1024];    // [side*512 + (h*32+lp)*2 + rp]

  const int t   = threadIdx.x;
  const int blk = blockIdx.x;
  const int b   = blk & 3;             // pins batch to XCD (blk%8 round-robin)
  const int q   = blk >> 2;
  const int row = b * NQ + q;

  const int h  = t >> 5;
  const int lp = t & 31;
  const int l  = lp >> 3;
  const int p  = lp & 7;

  // ---- softmax over the 32 (l,p) logits of this head (xor shuffles) ----
  const float logit = (float)fused[(size_t)row * 768 + 512 + t];
  float mxv = logit;
  #pragma unroll
  for (int m = 1; m < 32; m <<= 1) mxv = fmaxf(mxv, __shfl_xor(mxv, m));
  const float e = __expf(logit - mxv);
  float sum = e;
  #pragma unroll
  for (int m = 1; m < 32; m <<= 1) sum += __shfl_xor(sum, m);
  const float attnw = e / sum;

  // ---- location & bilinear setup ----
  const half2v o2 = *(const half2v*)(fused + (size_t)row * 768 + 2 * t);
  const float ox = (float)o2[0], oy = (float)o2[1];
  const int z = p & 3;                       // NP=8 split (2,4): z = p % 4
  const float rx = ref[((size_t)row * 4 + z) * 2 + 0];
  const float ry = ref[((size_t)row * 4 + z) * 2 + 1];
  const int Wl = lvl_w[l], Hl = lvl_h[l], st = lvl_s[l];

  const float px = fmaf(rx, (float)Wl, ox) - 0.5f;
  const float py = fmaf(ry, (float)Hl, oy) - 0.5f;
  const float x0f = floorf(px), y0f = floorf(py);
  const float wx = px - x0f, wy = py - y0f;
  const int x0 = (int)x0f, y0 = (int)y0f;
  const int x1 = x0 + 1,   y1 = y0 + 1;

  // x: one 128B segment based at xb covers slots xb (left) and xb+1 (right)
  const float mx0 = (x0 >= 0 && x0 < Wl) ? 1.f : 0.f;
  const float mx1 = (x1 >= 0 && x1 < Wl) ? 1.f : 0.f;
  const float my0 = (y0 >= 0 && y0 < Hl) ? 1.f : 0.f;
  const float my1 = (y1 >= 0 && y1 < Hl) ? 1.f : 0.f;
  const int xb  = min(max(x0, -1), Wl - 1);          // guard pages cover x=-1/W
  const int cy0 = min(max(y0, 0), Hl - 1);
  const int cy1 = min(max(y1, 0), Hl - 1);

  const int bh   = b * NH + h;
  const int lbase = bh * S_TOTAL + st;
  const float wlc = attnw * (1.f - wx) * mx0;
  const float wrc = attnw * wx * mx1;

  addr_s[2 * t + 0] = (lbase + cy0 * Wl + xb) * 32;
  addr_s[2 * t + 1] = (lbase + cy1 * Wl + xb) * 32;
  w2_s[2 * t + 0]       = wlc * (1.f - wy) * my0;   // left,  top row
  w2_s[2 * t + 1]       = wlc * wy * my1;           // left,  bottom row
  w2_s[512 + 2 * t + 0] = wrc * (1.f - wy) * my0;   // right, top row
  w2_s[512 + 2 * t + 1] = wrc * wy * my1;           // right, bottom row
  __syncthreads();

  // ---- phase 2: lane g = (ph, side, chquad) within head group ----
  const int g  = t & 31;
  const int c  = g & 7;           // channel quad: channels 4c..4c+3
  const int sd = (g >> 3) & 1;    // 0 = left corner, 1 = right corner
  const int ph = g >> 4;          // point parity
  const int ldoff = sd * 32 + 4 * c;
  const int wbase = sd << 9;

  // addresses first (LDS), then issue ALL 32 global loads, then FENCE.
  int at[16], ab[16];
  #pragma unroll
  for (int i = 0; i < 16; ++i) {
    const int idx = ((h << 5) + 2 * i + ph) * 2;
    at[i] = addr_s[idx];
    ab[i] = addr_s[idx + 1];
  }

  half4v vt[16], vb[16];
  #pragma unroll
  for (int i = 0; i < 16; ++i) {
    vt[i] = *(const half4v*)(vproj + at[i] + ldoff);
    vb[i] = *(const half4v*)(vproj + ab[i] + ldoff);
  }
  // Hard scheduling fence: no FMA may hoist above, no load may sink below.
  // Forces all 32 gathers genuinely in flight (64 VGPRs of results live).
  __builtin_amdgcn_sched_barrier(0);

  float a0 = 0.f, a1 = 0.f, a2 = 0.f, a3 = 0.f;
  #pragma unroll
  for (int i = 0; i < 16; ++i) {
    const int idx = ((h << 5) + 2 * i + ph) * 2;
    const float wt = w2_s[wbase + idx];
    const float wb = w2_s[wbase + idx + 1];
    a0 = fmaf(wt, (float)vt[i][0], a0); a1 = fmaf(wt, (float)vt[i][1], a1);
    a2 = fmaf(wt, (float)vt[i][2], a2); a3 = fmaf(wt, (float)vt[i][3], a3);
    a0 = fmaf(wb, (float)vb[i][0], a0); a1 = fmaf(wb, (float)vb[i][1], a1);
    a2 = fmaf(wb, (float)vb[i][2], a2); a3 = fmaf(wb, (float)vb[i][3], a3);
  }

  // reduce over side (xor 8) and point parity (xor 16)
  a0 += __shfl_xor(a0, 8);  a1 += __shfl_xor(a1, 8);
  a2 += __shfl_xor(a2, 8);  a3 += __shfl_xor(a3, 8);
  a0 += __shfl_xor(a0, 16); a1 += __shfl_xor(a1, 16);
  a2 += __shfl_xor(a2, 16); a3 += __shfl_xor(a3, 16);

  if (g < 8) {    // sd==0 && ph==0: 8 lanes own the 8 channel quads
    float4 o; o.x = a0; o.y = a1; o.z = a2; o.w = a3;
    *(float4*)(out + (size_t)row * 256 + (h << 5) + 4 * c) = o;
  }
}

extern "C" void kernel_launch(void* const* d_in, const int* in_sizes, int n_in,
                              void* d_out, int out_size, void* d_ws, size_t ws_size,
                              hipStream_t stream) {
  const float* query  = (const float*)d_in[0];  // [4,10000,256]
  const float* value  = (const float*)d_in[1];  // [4,19560,256]
  const float* refpts = (const float*)d_in[2];  // [4,10000,4,2]
  const float* w_off  = (const float*)d_in[3];  // [256,512]
  const float* b_off  = (const float*)d_in[4];  // [512]
  const float* w_attn = (const float*)d_in[5];  // [256,256]
  const float* b_attn = (const float*)d_in[6];  // [256]
  const float* w_val  = (const float*)d_in[7];  // [256,256]
  const float* b_val  = (const float*)d_in[8];  // [256]
  float* out = (float*)d_out;

  // workspace layout (16B-multiple segments; 256B guards around vh for the
  // x=-1 / x=W edge reads, whose weights are zero)
  char* p = (char*)d_ws;
  p += 256;                                                         // front guard
  _Float16* vh    = (_Float16*)p;  p += (size_t)VROWS * 256 * 2;    // 40.1 MB
  p += 256;                                                         // back guard
  _Float16* wT768 = (_Float16*)p;  p += (size_t)768 * 256 * 2;      // swizzled
  _Float16* wvaT  = (_Float16*)p;  p += (size_t)256 * 256 * 2;      // swizzled
  _Float16* fused_h = (_Float16*)p; p += (size_t)NROW * 768 * 2;    // 61.4 MB

  // prep: all weight transposes in one launch
  prep_weights<<<1024, 256, 0, stream>>>(w_off, w_attn, w_val, wT768, wvaT);

  // GEMMs: A register-resident, B chunks via LDS.
  // v = value@w_val -> [B,H,S,32] swizzled; fused = query@[w_off|w_attn]
  gemm5<256, 1, true><<<dim3((VROWS + 127) / 128, 1), 256, 0, stream>>>(
      value, wvaT, b_val, b_val, 1 << 30, vh, VROWS);
  gemm5<768, 2, false><<<dim3((NROW + 127) / 128, 2), 256, 0, stream>>>(
      query, wT768, b_off, b_attn, 512, fused_h, NROW);

  // softmax + sample + weighted sum
  msda_sample<<<dim3(NROW), 256, 0, stream>>>(vh, fused_h, refpts, out);
}

// Round 3
// 398.207 us; speedup vs baseline: 1.0898x; 1.0362x over previous
//
#include <hip/hip_runtime.h>

// Problem constants (fixed by setup_inputs)
#define BATCH    4
#define NQ       10000
#define EMB      256
#define NH       8
#define DH       32
#define NL       4
#define NP       8
#define S_TOTAL  19560
#define NROW     (BATCH * NQ)          // 40000
#define VROWS    (BATCH * S_TOTAL)     // 78240

typedef _Float16 half8 __attribute__((ext_vector_type(8)));
typedef _Float16 half4v __attribute__((ext_vector_type(4)));
typedef _Float16 half2v __attribute__((ext_vector_type(2)));
typedef float floatx4 __attribute__((ext_vector_type(4)));

// ---------------------------------------------------------------------------
// One-shot weight prep: transpose+swizzle all three weight matrices to f16.
// Logical row n (0..1023): [0,512) w_off -> wT768, [512,768) w_attn -> wT768,
// [768,1024) w_val (256 rows) -> wvaT. Swizzle: 16B chunk c of row n lands at
// chunk c ^ (n&7).
// ---------------------------------------------------------------------------
__global__ __launch_bounds__(256) void prep_weights(
    const float* __restrict__ w_off, const float* __restrict__ w_attn,
    const float* __restrict__ w_val, _Float16* __restrict__ wT768,
    _Float16* __restrict__ wvaT) {
  const int tid = blockIdx.x * 256 + threadIdx.x;   // over 1024*256
  const int n = tid >> 8, k = tid & 255;
  const int c = k >> 3, e = k & 7;
  const int swz = ((c ^ (n & 7)) << 3) + e;
  float v;
  _Float16* dst;
  if (n < 512)      { v = w_off[(size_t)k * 512 + n];          dst = wT768 + (size_t)n * 256; }
  else if (n < 768) { v = w_attn[(size_t)k * 256 + (n - 512)]; dst = wT768 + (size_t)n * 256; }
  else              { v = w_val[(size_t)k * 256 + (n - 768)];  dst = wvaT + (size_t)(n - 768) * 256; }
  dst[swz] = (_Float16)v;
}

// ---------------------------------------------------------------------------
// MFMA GEMM round-11: A-register-resident + B-chunk-in-LDS, 3 blocks/CU.
//   C = A[M,256]_f32 @ WTs[NC,256]^T + bias(col-select)
// Changes vs gemm5 (theory: the ~195us non-msda budget is mostly here):
//   1. Register-prefetch double-buffer (T14): chunk ch+1's 8 half8 global
//      loads are issued BEFORE computing chunk ch; ds_write lands after the
//      post-compute barrier. Hides ~500cy L2 latency under MFMA+stores.
//   2. SWZ path swaps MFMA operands: mfma(b, a, acc). C/D layout
//      (col=lane&15, row=(lane>>4)*4+reg) then puts the 4 acc regs on 4
//      CONSECUTIVE channels of one output row -> one coalesced 8B half4
//      store per (i,j): 8 stores/thread/chunk instead of 32 x 2B scatter.
// ---------------------------------------------------------------------------
template <int NC, int NYS, bool SWZ>
__global__ __launch_bounds__(256, 3) void gemm6(
    const float* __restrict__ A, const _Float16* __restrict__ WTs,
    const float* __restrict__ bias0, const float* __restrict__ bias1,
    int splitc, _Float16* __restrict__ C, int M) {
  __shared__ _Float16 bsm[64 * 256];   // 32 KB B chunk (swizzled rows)
  const int t = threadIdx.x;
  const int wave = t >> 6, lane = t & 63;
  const int l15 = lane & 15, quad = lane >> 4;
  const int m0 = blockIdx.x * 128 + wave * 32;
  const int nlo = blockIdx.y * (NC / NYS);
  const int nchunks = (NC / NYS) / 64;

  const _Float16* src = WTs + (size_t)nlo * 256;

  // ---- issue chunk-0 B loads first (latency covered by A load+convert) ----
  half8 pb[8];
  #pragma unroll
  for (int i = 0; i < 8; ++i)
    pb[i] = *(const half8*)(src + t * 8 + i * 2048);

  // ---- load + convert the wave's A slice (32 rows x 256) ----
  half8 a[2][8];
  #pragma unroll
  for (int i = 0; i < 2; ++i) {
    const float* Ar = A + (size_t)min(m0 + 16 * i + l15, M - 1) * 256 + quad * 8;
    #pragma unroll
    for (int ks = 0; ks < 8; ++ks) {
      const float4 f0 = *(const float4*)(Ar + ks * 32);
      const float4 f1 = *(const float4*)(Ar + ks * 32 + 4);
      a[i][ks][0] = (_Float16)f0.x; a[i][ks][1] = (_Float16)f0.y;
      a[i][ks][2] = (_Float16)f0.z; a[i][ks][3] = (_Float16)f0.w;
      a[i][ks][4] = (_Float16)f1.x; a[i][ks][5] = (_Float16)f1.y;
      a[i][ks][6] = (_Float16)f1.z; a[i][ks][7] = (_Float16)f1.w;
    }
  }

  #pragma unroll
  for (int i = 0; i < 8; ++i)
    *(half8*)&bsm[t * 8 + i * 2048] = pb[i];
  __syncthreads();

  for (int ch = 0; ch < nchunks; ++ch) {
    // prefetch next chunk into registers (overlaps with compute below)
    if (ch + 1 < nchunks) {
      const _Float16* s2 = src + (size_t)(ch + 1) * 64 * 256;
      #pragma unroll
      for (int i = 0; i < 8; ++i)
        pb[i] = *(const half8*)(s2 + t * 8 + i * 2048);
    }

    floatx4 acc[2][4] = {};
    #pragma unroll
    for (int ks = 0; ks < 8; ++ks) {
      half8 b[4];
      #pragma unroll
      for (int j = 0; j < 4; ++j)
        b[j] = *(const half8*)&bsm[(16 * j + l15) * 256 +
                                   ((((ks * 4 + quad) ^ (l15 & 7))) << 3)];
      if constexpr (SWZ) {
        #pragma unroll
        for (int j = 0; j < 4; ++j)
          #pragma unroll
          for (int i = 0; i < 2; ++i)
            acc[i][j] = __builtin_amdgcn_mfma_f32_16x16x32_f16(b[j], a[i][ks], acc[i][j], 0, 0, 0);
      } else {
        #pragma unroll
        for (int j = 0; j < 4; ++j)
          #pragma unroll
          for (int i = 0; i < 2; ++i)
            acc[i][j] = __builtin_amdgcn_mfma_f32_16x16x32_f16(a[i][ks], b[j], acc[i][j], 0, 0, 0);
      }
    }

    const int nc0 = nlo + ch * 64;

    if constexpr (SWZ) {
      // acc[i][j][r] = C[m0+16i+l15][nc0+16j+quad*4+r] : 4 consecutive
      // channels of one output row -> one 8B half4 coalesced store.
      #pragma unroll
      for (int j = 0; j < 4; ++j) {
        const int col0 = nc0 + 16 * j + quad * 4;
        const int h = col0 >> 5, c0 = col0 & 31;
        const float4 bq = *(const float4*)(bias0 + col0);
        #pragma unroll
        for (int i = 0; i < 2; ++i) {
          const int row = m0 + 16 * i + l15;
          if (row < M) {
            const int b = row / S_TOTAL;
            const int s = row - b * S_TOTAL;
            half4v pk;
            pk[0] = (_Float16)(acc[i][j][0] + bq.x);
            pk[1] = (_Float16)(acc[i][j][1] + bq.y);
            pk[2] = (_Float16)(acc[i][j][2] + bq.z);
            pk[3] = (_Float16)(acc[i][j][3] + bq.w);
            *(half4v*)(C + ((((size_t)b * NH + h) * S_TOTAL + s) * 32 + c0)) = pk;
          }
        }
      }
    } else {
      float bc[4];
      #pragma unroll
      for (int j = 0; j < 4; ++j) {
        const int col = nc0 + 16 * j + l15;
        bc[j] = (col < splitc) ? bias0[col] : bias1[col - splitc];
      }
      #pragma unroll
      for (int i = 0; i < 2; ++i) {
        #pragma unroll
        for (int r = 0; r < 4; ++r) {
          const int row = m0 + 16 * i + quad * 4 + r;
          if (row < M) {
            #pragma unroll
            for (int j = 0; j < 4; ++j)
              C[(size_t)row * NC + nc0 + 16 * j + l15] =
                  (_Float16)(acc[i][j][r] + bc[j]);
          }
        }
      }
    }

    __syncthreads();               // all waves done reading bsm
    if (ch + 1 < nchunks) {
      #pragma unroll
      for (int i = 0; i < 8; ++i)
        *(half8*)&bsm[t * 8 + i * 2048] = pb[i];
      __syncthreads();
    }
  }
}

// ---------------------------------------------------------------------------
// Fused softmax + deformable bilinear sampling. vproj [B,H,S,32];
// XCD-pinned batches; rowpair 2-segment gathers.
// Round-11: exact round-8 structure restored (195.5us measured). The only
// delta vs round-8: merged weight array w2_s (side-select = +512 address
// offset instead of two cndmask chains). sched_barrier REMOVED — r10 proved
// it costs 23us (blocked beneficial interleaving, occupancy 64->55) while
// failing to force MLP (VGPR stayed 44).
// ---------------------------------------------------------------------------
__global__ __launch_bounds__(256, 4) void msda_sample(
    const _Float16* __restrict__ vproj,     // [B,H,S,32] f16 (+guards)
    const _Float16* __restrict__ fused,     // [B*Q, 768] f16: off(512)|logit(256)
    const float* __restrict__ ref,          // [B*Q, 4, 2] f32
    float* __restrict__ out) {              // [B*Q, 256] f32
  const int lvl_h[NL] = {92, 46, 23, 12};
  const int lvl_w[NL] = {160, 80, 40, 20};
  const int lvl_s[NL] = {0, 14720, 18400, 19320};

  __shared__ int   addr_s[512];   // [(h*32+lp)*2 + rp]
  __shared__ float w2_s[1024];    // [side*512 + (h*32+lp)*2 + rp]

  const int t   = threadIdx.x;
  const int blk = blockIdx.x;
  const int b   = blk & 3;             // pins batch to XCD (blk%8 round-robin)
  const int q   = blk >> 2;
  const int row = b * NQ + q;

  const int h  = t >> 5;
  const int lp = t & 31;
  const int l  = lp >> 3;
  const int p  = lp & 7;

  // ---- softmax over the 32 (l,p) logits of this head (xor shuffles) ----
  const float logit = (float)fused[(size_t)row * 768 + 512 + t];
  float mxv = logit;
  #pragma unroll
  for (int m = 1; m < 32; m <<= 1) mxv = fmaxf(mxv, __shfl_xor(mxv, m));
  const float e = __expf(logit - mxv);
  float sum = e;
  #pragma unroll
  for (int m = 1; m < 32; m <<= 1) sum += __shfl_xor(sum, m);
  const float attnw = e / sum;

  // ---- location & bilinear setup ----
  const half2v o2 = *(const half2v*)(fused + (size_t)row * 768 + 2 * t);
  const float ox = (float)o2[0], oy = (float)o2[1];
  const int z = p & 3;                       // NP=8 split (2,4): z = p % 4
  const float rx = ref[((size_t)row * 4 + z) * 2 + 0];
  const float ry = ref[((size_t)row * 4 + z) * 2 + 1];
  const int Wl = lvl_w[l], Hl = lvl_h[l], st = lvl_s[l];

  const float px = fmaf(rx, (float)Wl, ox) - 0.5f;
  const float py = fmaf(ry, (float)Hl, oy) - 0.5f;
  const float x0f = floorf(px), y0f = floorf(py);
  const float wx = px - x0f, wy = py - y0f;
  const int x0 = (int)x0f, y0 = (int)y0f;
  const int x1 = x0 + 1,   y1 = y0 + 1;

  // x: one 128B segment based at xb covers slots xb (left) and xb+1 (right)
  const float mx0 = (x0 >= 0 && x0 < Wl) ? 1.f : 0.f;
  const float mx1 = (x1 >= 0 && x1 < Wl) ? 1.f : 0.f;
  const float my0 = (y0 >= 0 && y0 < Hl) ? 1.f : 0.f;
  const float my1 = (y1 >= 0 && y1 < Hl) ? 1.f : 0.f;
  const int xb  = min(max(x0, -1), Wl - 1);          // guard pages cover x=-1/W
  const int cy0 = min(max(y0, 0), Hl - 1);
  const int cy1 = min(max(y1, 0), Hl - 1);

  const int bh   = b * NH + h;
  const int lbase = bh * S_TOTAL + st;
  const float wlc = attnw * (1.f - wx) * mx0;
  const float wrc = attnw * wx * mx1;

  addr_s[2 * t + 0] = (lbase + cy0 * Wl + xb) * 32;
  addr_s[2 * t + 1] = (lbase + cy1 * Wl + xb) * 32;
  w2_s[2 * t + 0]       = wlc * (1.f - wy) * my0;   // left,  top row
  w2_s[2 * t + 1]       = wlc * wy * my1;           // left,  bottom row
  w2_s[512 + 2 * t + 0] = wrc * (1.f - wy) * my0;   // right, top row
  w2_s[512 + 2 * t + 1] = wrc * wy * my1;           // right, bottom row
  __syncthreads();

  // ---- phase 2: lane g = (ph, side, chquad) within head group ----
  const int g  = t & 31;
  const int c  = g & 7;           // channel quad: channels 4c..4c+3
  const int sd = (g >> 3) & 1;    // 0 = left corner, 1 = right corner
  const int ph = g >> 4;          // point parity
  const int ldoff = sd * 32 + 4 * c;
  const int wbase = sd << 9;

  // load everything first (32 independent loads in flight), then fma
  half4v vt[16], vb[16];
  float wt[16], wb[16];
  #pragma unroll
  for (int i = 0; i < 16; ++i) {
    const int idx = ((h << 5) + 2 * i + ph) * 2;
    const int at = addr_s[idx], ab = addr_s[idx + 1];
    wt[i] = w2_s[wbase + idx];
    wb[i] = w2_s[wbase + idx + 1];
    vt[i] = *(const half4v*)(vproj + at + ldoff);
    vb[i] = *(const half4v*)(vproj + ab + ldoff);
  }

  float a0 = 0.f, a1 = 0.f, a2 = 0.f, a3 = 0.f;
  #pragma unroll
  for (int i = 0; i < 16; ++i) {
    a0 = fmaf(wt[i], (float)vt[i][0], a0); a1 = fmaf(wt[i], (float)vt[i][1], a1);
    a2 = fmaf(wt[i], (float)vt[i][2], a2); a3 = fmaf(wt[i], (float)vt[i][3], a3);
    a0 = fmaf(wb[i], (float)vb[i][0], a0); a1 = fmaf(wb[i], (float)vb[i][1], a1);
    a2 = fmaf(wb[i], (float)vb[i][2], a2); a3 = fmaf(wb[i], (float)vb[i][3], a3);
  }

  // reduce over side (xor 8) and point parity (xor 16)
  a0 += __shfl_xor(a0, 8);  a1 += __shfl_xor(a1, 8);
  a2 += __shfl_xor(a2, 8);  a3 += __shfl_xor(a3, 8);
  a0 += __shfl_xor(a0, 16); a1 += __shfl_xor(a1, 16);
  a2 += __shfl_xor(a2, 16); a3 += __shfl_xor(a3, 16);

  if (g < 8) {    // sd==0 && ph==0: 8 lanes own the 8 channel quads
    float4 o; o.x = a0; o.y = a1; o.z = a2; o.w = a3;
    *(float4*)(out + (size_t)row * 256 + (h << 5) + 4 * c) = o;
  }
}

extern "C" void kernel_launch(void* const* d_in, const int* in_sizes, int n_in,
                              void* d_out, int out_size, void* d_ws, size_t ws_size,
                              hipStream_t stream) {
  const float* query  = (const float*)d_in[0];  // [4,10000,256]
  const float* value  = (const float*)d_in[1];  // [4,19560,256]
  const float* refpts = (const float*)d_in[2];  // [4,10000,4,2]
  const float* w_off  = (const float*)d_in[3];  // [256,512]
  const float* b_off  = (const float*)d_in[4];  // [512]
  const float* w_attn = (const float*)d_in[5];  // [256,256]
  const float* b_attn = (const float*)d_in[6];  // [256]
  const float* w_val  = (const float*)d_in[7];  // [256,256]
  const float* b_val  = (const float*)d_in[8];  // [256]
  float* out = (float*)d_out;

  // workspace layout (16B-multiple segments; 256B guards around vh for the
  // x=-1 / x=W edge reads, whose weights are zero)
  char* p = (char*)d_ws;
  p += 256;                                                         // front guard
  _Float16* vh    = (_Float16*)p;  p += (size_t)VROWS * 256 * 2;    // 40.1 MB
  p += 256;                                                         // back guard
  _Float16* wT768 = (_Float16*)p;  p += (size_t)768 * 256 * 2;      // swizzled
  _Float16* wvaT  = (_Float16*)p;  p += (size_t)256 * 256 * 2;      // swizzled
  _Float16* fused_h = (_Float16*)p; p += (size_t)NROW * 768 * 2;    // 61.4 MB

  // prep: all weight transposes in one launch
  prep_weights<<<1024, 256, 0, stream>>>(w_off, w_attn, w_val, wT768, wvaT);

  // GEMMs: A register-resident, B chunks via LDS, register-prefetch dbuf.
  // v = value@w_val -> [B,H,S,32] swizzled (coalesced half4 stores);
  // fused = query@[w_off|w_attn]
  gemm6<256, 1, true><<<dim3((VROWS + 127) / 128, 1), 256, 0, stream>>>(
      value, wvaT, b_val, b_val, 1 << 30, vh, VROWS);
  gemm6<768, 2, false><<<dim3((NROW + 127) / 128, 2), 256, 0, stream>>>(
      query, wT768, b_off, b_attn, 512, fused_h, NROW);

  // softmax + sample + weighted sum
  msda_sample<<<dim3(NROW), 256, 0, stream>>>(vh, fused_h, refpts, out);
}